// Round 11
// baseline (200.632 us; speedup 1.0000x reference)
//
#include <hip/hip_runtime.h>
#include <hip/hip_bf16.h>

// SNN: B=2048, NI=1024, NH=2048, NO=10, T=128, BETA=0.95, THR=1.0
// K1: cur1 = x @ w1^T + b1 via bf16x3 MFMA (round-8 verified, frozen).
// K2: chunked LIF + time-as-M MFMA. r11: occupancy 2x — GB=4, batch split
//     across 2 waves (16 neurons/lane), LDS 79.5 KB -> 2 blocks/CU.

#define B_   2048
#define NI_  1024
#define NH_  2048
#define NO_  10
#define T_   128
#define GB_  4
#define NBLK (B_ / GB_)   // 512 blocks
#define TC_  32
#define NCH  (T_ / TC_)

typedef __attribute__((ext_vector_type(8))) short short8;
typedef __attribute__((ext_vector_type(4))) float f32x4;
typedef __attribute__((ext_vector_type(4))) unsigned int u32x4;

// bf16 round-to-nearest-even of an f32, low 16 bits.
__device__ __forceinline__ unsigned int bf16_rne(float f) {
  unsigned int u = __float_as_uint(f);
  return (u + 0x7FFFu + ((u >> 16) & 1u)) >> 16;
}

// ---------------- Kernel 1: cur1 = x @ w1^T + b1 (bf16x3 MFMA) --------------
#define G_ASTRIDE 144
#define G_AOFF    0
#define G_BOFF    (128 * G_ASTRIDE)
#define G_SMEM    (2 * 128 * G_ASTRIDE)

__global__ __launch_bounds__(512, 4) void gemm_cur1(
    const float* __restrict__ x, const float* __restrict__ w1,
    const float* __restrict__ b1, float* __restrict__ cur1) {
  __shared__ __align__(16) char smem[G_SMEM];
  const int tid = threadIdx.x;
  const int lane = tid & 63;
  const int wv = tid >> 6;
  const int wm = wv >> 2;
  const int wn = wv & 3;
  const int n15 = lane & 15;
  const int g = lane >> 4;
  const int brow = blockIdx.y * 128;
  const int bcol = blockIdx.x * 128;

  const int r_st = tid >> 3;
  const int kq = tid & 7;

  f32x4 acc[4][2];
#pragma unroll
  for (int tm = 0; tm < 4; ++tm)
#pragma unroll
    for (int tn = 0; tn < 2; ++tn) acc[tm][tn] = f32x4{0, 0, 0, 0};

  for (int kt = 0; kt < NI_; kt += 32) {
#pragma unroll
    for (int p = 0; p < 2; ++p) {
      const int r = r_st + p * 64;
      const float4 va = *reinterpret_cast<const float4*>(
          &x[(size_t)(brow + r) * NI_ + kt + kq * 4]);
      const float4 vb = *reinterpret_cast<const float4*>(
          &w1[(size_t)(bcol + r) * NI_ + kt + kq * 4]);
      const float fa[4] = {va.x, va.y, va.z, va.w};
      const float fb[4] = {vb.x, vb.y, vb.z, vb.w};
      unsigned ha[4], la[4], hb[4], lb[4];
#pragma unroll
      for (int c = 0; c < 4; ++c) {
        ha[c] = bf16_rne(fa[c]);
        la[c] = bf16_rne(fa[c] - __uint_as_float(ha[c] << 16));
        hb[c] = bf16_rne(fb[c]);
        lb[c] = bf16_rne(fb[c] - __uint_as_float(hb[c] << 16));
      }
      char* arow = smem + G_AOFF + r * G_ASTRIDE;
      char* brw  = smem + G_BOFF + r * G_ASTRIDE;
      *reinterpret_cast<uint2*>(arow + kq * 8) =
          uint2{ha[0] | (ha[1] << 16), ha[2] | (ha[3] << 16)};
      *reinterpret_cast<uint2*>(arow + 64 + kq * 8) =
          uint2{la[0] | (la[1] << 16), la[2] | (la[3] << 16)};
      *reinterpret_cast<uint2*>(brw + kq * 8) =
          uint2{hb[0] | (hb[1] << 16), hb[2] | (hb[3] << 16)};
      *reinterpret_cast<uint2*>(brw + 64 + kq * 8) =
          uint2{lb[0] | (lb[1] << 16), lb[2] | (lb[3] << 16)};
    }
    __syncthreads();

    short8 ah[4], al[4], bh2[2], bl2[2];
#pragma unroll
    for (int tm = 0; tm < 4; ++tm) {
      const char* p = smem + G_AOFF + (wm * 64 + tm * 16 + n15) * G_ASTRIDE;
      ah[tm] = *reinterpret_cast<const short8*>(p + g * 16);
      al[tm] = *reinterpret_cast<const short8*>(p + 64 + g * 16);
    }
#pragma unroll
    for (int tn = 0; tn < 2; ++tn) {
      const char* p = smem + G_BOFF + (wn * 32 + tn * 16 + n15) * G_ASTRIDE;
      bh2[tn] = *reinterpret_cast<const short8*>(p + g * 16);
      bl2[tn] = *reinterpret_cast<const short8*>(p + 64 + g * 16);
    }
#pragma unroll
    for (int tm = 0; tm < 4; ++tm)
#pragma unroll
      for (int tn = 0; tn < 2; ++tn) {
        acc[tm][tn] = __builtin_amdgcn_mfma_f32_16x16x32_bf16(
            ah[tm], bh2[tn], acc[tm][tn], 0, 0, 0);
        acc[tm][tn] = __builtin_amdgcn_mfma_f32_16x16x32_bf16(
            ah[tm], bl2[tn], acc[tm][tn], 0, 0, 0);
        acc[tm][tn] = __builtin_amdgcn_mfma_f32_16x16x32_bf16(
            al[tm], bh2[tn], acc[tm][tn], 0, 0, 0);
      }
    __syncthreads();
  }

#pragma unroll
  for (int tn = 0; tn < 2; ++tn) {
    const int col = bcol + wn * 32 + tn * 16 + n15;
    const float bias = b1[col];
#pragma unroll
    for (int tm = 0; tm < 4; ++tm) {
      const int rowb = brow + wm * 64 + tm * 16 + g * 4;
#pragma unroll
      for (int r = 0; r < 4; ++r)
        cur1[(size_t)(rowb + r) * NH_ + col] = acc[tm][tn][r] + bias;
    }
  }
}

// ---------------- Kernel 2: chunked LIF + time-as-M MFMA --------------------
// 8 waves: hf = w>>2 (neuron half), bq = w&3 (batch). Lane owns 16 neurons
// h = hf*1024 + lane*16 + i. Bits word k = h/32 = hf*32 + (lane>>1),
// halfword (lane&1). Phase-2/3/4 formulas identical to r10 (b<4).
// LDS map (bytes):
//   bits u32[4 b][32 tl][65]            at 0      (33280)
//   lut  uint2[16]                      at 33280  (128)
//   comb f32[8 w][4 b][2][4][10][4]     at 33408  (40960)
//   stag f32[4 b][32 tl][10]            at 74368  (5120)
#define BITS_OFF 0
#define LUT_OFF  33280
#define COMB_OFF 33408
#define STAG_OFF 74368
#define SMEM_BYTES 79488

__global__ __launch_bounds__(512, 4) void snn_loop(
    const float* __restrict__ cur1, const float* __restrict__ w2,
    const float* __restrict__ b2, float* __restrict__ spk2_rec,
    float* __restrict__ mem2_rec) {
  extern __shared__ char smem[];
  uint2* lutw = reinterpret_cast<uint2*>(smem + LUT_OFF);
  const uint2* lut = lutw;
  float* comb = reinterpret_cast<float*>(smem + COMB_OFF);
  float* stag = reinterpret_cast<float*>(smem + STAG_OFF);
  const int tid = threadIdx.x;
  const int lane = tid & 63;
  const int w = tid >> 6;
  const int hf = w >> 2;               // neuron half
  const int bq = w & 3;                // local batch
  const int bbase = blockIdx.x * GB_;
  const int bb = bbase + bq;

  if (tid < 16) {
    lutw[tid] = uint2{(tid & 1 ? 0x3F80u : 0u) | (tid & 2 ? 0x3F800000u : 0u),
                      (tid & 4 ? 0x3F80u : 0u) | (tid & 8 ? 0x3F800000u : 0u)};
  }

  // ---- layer-1 state: 16 contiguous h per lane ----
  float mem1[16], c1v[16], spk[16];
  {
    const float* base = cur1 + (size_t)bb * NH_ + hf * 1024 + lane * 16;
#pragma unroll
    for (int q = 0; q < 4; ++q) {
      const float4 v = *reinterpret_cast<const float4*>(base + q * 4);
      c1v[q * 4 + 0] = v.x; c1v[q * 4 + 1] = v.y;
      c1v[q * 4 + 2] = v.z; c1v[q * 4 + 3] = v.w;
    }
#pragma unroll
    for (int i = 0; i < 16; ++i) { mem1[i] = 0.0f; spk[i] = 0.0f; }
  }

  // ---- w2 B-fragments in registers (hi/lo split) — verified ----
  u32x4 bhi[8], blo[8];
  {
    const int o = lane & 15;
    const int koff = (lane >> 4) * 8;
#pragma unroll
    for (int kbl = 0; kbl < 8; ++kbl) {
      const int kb = w * 8 + kbl;
      unsigned int hw[4], lw[4];
#pragma unroll
      for (int p = 0; p < 4; ++p) {
        unsigned int h0 = 0, h1 = 0, l0 = 0, l1 = 0;
        if (o < NO_) {
          const int k = kb * 32 + koff + p * 2;
          const float f0 = w2[(size_t)o * NH_ + k];
          const float f1 = w2[(size_t)o * NH_ + k + 1];
          h0 = bf16_rne(f0);
          h1 = bf16_rne(f1);
          l0 = bf16_rne(f0 - __uint_as_float(h0 << 16));
          l1 = bf16_rne(f1 - __uint_as_float(h1 << 16));
        }
        hw[p] = h0 | (h1 << 16);
        lw[p] = l0 | (l1 << 16);
      }
      bhi[kbl] = u32x4{hw[0], hw[1], hw[2], hw[3]};
      blo[kbl] = u32x4{lw[0], lw[1], lw[2], lw[3]};
    }
  }

  // ---- layer-2 state: wave bq (hf==0), lanes < NO_ ----
  float mem2 = 0.0f, spk2 = 0.0f, b2v = 0.0f;
  float *srec = nullptr, *mrec = nullptr;
  if (hf == 0 && lane < NO_) {
    b2v = b2[lane];
    srec = spk2_rec + (size_t)bb * NO_ + lane;
    mrec = mem2_rec + (size_t)bb * NO_ + lane;
  }

  const int n15 = lane & 15;
  const int g = lane >> 4;

  // ---- phase-3' per-lane offsets (hf==0 waves only use these) ----
  int rd_off[5], wr_off[5];
#pragma unroll
  for (int j = 0; j < 5; ++j) {
    const int q = lane * 5 + j;          // 0..319 within batch bq
    const int tb = q / 160;
    const int r160 = q - tb * 160;
    const int g2 = r160 / 40;
    const int r40 = r160 - g2 * 40;
    const int n = r40 >> 2;
    const int r = r40 & 3;
    rd_off[j] = bq * 320 + q;            // + ww*1280 in the loop
    wr_off[j] = (bq * TC_ + tb * 16 + g2 * 4 + r) * 10 + n;
  }

  // bits halfword pointer: word (bq*32+tl)*65 + hf*32 + (lane>>1), half lane&1
  unsigned short* bitsw = reinterpret_cast<unsigned short*>(smem) +
      ((bq * TC_) * 65 + hf * 32 + (lane >> 1)) * 2 + (lane & 1);
  const unsigned char* bytes = reinterpret_cast<const unsigned char*>(smem);

  for (int ch = 0; ch < NCH; ++ch) {
    // ---- phase 1: LIF for TC_ steps; descending-i addc bit collect ----
    for (int tl = 0; tl < TC_; ++tl) {
      unsigned W = 0;
#pragma unroll
      for (int i = 15; i >= 0; --i) {
        float m = fmaf(0.95f, mem1[i], c1v[i]);
        m = m - spk[i];
        mem1[i] = m;
        const bool c = m > 1.0f;
        W = W + W + (c ? 1u : 0u);
        spk[i] = c ? 1.0f : 0.0f;
      }
      bitsw[tl * 130] = (unsigned short)W;
    }
    __syncthreads();  // B1: bits ready (also fences comb vs prev P3')

    // ---- phase 2: MFMA partials over this wave's K-chunk, 4 batches ----
    for (int b = 0; b < GB_; ++b) {
#pragma unroll
      for (int tb = 0; tb < 2; ++tb) {
        f32x4 acc = {0.0f, 0.0f, 0.0f, 0.0f};
#pragma unroll
        for (int kbl = 0; kbl < 8; ++kbl) {
          const int kb = w * 8 + kbl;
          const unsigned byt =
              bytes[(b * 2080 + tb * 1040 + n15 * 65 + kb) * 4 + g];
          const uint2 lo2 = lut[byt & 15u];
          const uint2 hi2 = lut[byt >> 4];
          const u32x4 A = {lo2.x, lo2.y, hi2.x, hi2.y};
          const short8 af = __builtin_bit_cast(short8, A);
          acc = __builtin_amdgcn_mfma_f32_16x16x32_bf16(
              af, __builtin_bit_cast(short8, bhi[kbl]), acc, 0, 0, 0);
          acc = __builtin_amdgcn_mfma_f32_16x16x32_bf16(
              af, __builtin_bit_cast(short8, blo[kbl]), acc, 0, 0, 0);
        }
        if (n15 < NO_)
          *reinterpret_cast<f32x4*>(
              &comb[w * 1280 + b * 320 + tb * 160 + g * 40 + n15 * 4]) = acc;
      }
    }
    __syncthreads();  // B2: comb ready; bits dead

    if (hf == 0) {
      // ---- phase 3': sum 8 wave-partials for OWN batch -> stag ----
#pragma unroll
      for (int j = 0; j < 5; ++j) {
        float s = 0.0f;
#pragma unroll
        for (int ww = 0; ww < 8; ++ww) s += comb[ww * 1280 + rd_off[j]];
        stag[wr_off[j]] = s;
      }
      // stag slice [bq] written and read only by this wave (lgkmcnt)

      // ---- phase 4: mem2 scan ----
      if (lane < NO_) {
        for (int tl = 0; tl < TC_; ++tl) {
          const float cur2 = stag[(bq * TC_ + tl) * 10 + lane] + b2v;
          float m = fmaf(0.95f, mem2, cur2);
          m = m - spk2;
          mem2 = m;
          spk2 = (m > 1.0f) ? 1.0f : 0.0f;
          const int t = ch * TC_ + tl;
          srec[(size_t)t * (B_ * NO_)] = spk2;
          mrec[(size_t)t * (B_ * NO_)] = m;
        }
      }
    }
    // no barrier: next P1 writes bits (dead since B2); comb overwrite is
    // fenced by the next B1; stag/comb reads are done before this wave's B1.
  }
}

// ---------------------------------------------------------------------------
extern "C" void kernel_launch(void* const* d_in, const int* in_sizes, int n_in,
                              void* d_out, int out_size, void* d_ws, size_t ws_size,
                              hipStream_t stream) {
  const float* x  = (const float*)d_in[0];
  const float* w1 = (const float*)d_in[1];
  const float* b1 = (const float*)d_in[2];
  const float* w2 = (const float*)d_in[3];
  const float* b2 = (const float*)d_in[4];
  float* out = (float*)d_out;
  float* cur1 = (float*)d_ws;

  float* spk2_rec = out;
  float* mem2_rec = out + (size_t)T_ * B_ * NO_;

  (void)hipFuncSetAttribute(reinterpret_cast<const void*>(snn_loop),
                            hipFuncAttributeMaxDynamicSharedMemorySize,
                            SMEM_BYTES);

  dim3 g1(NH_ / 128, B_ / 128);
  gemm_cur1<<<g1, 512, 0, stream>>>(x, w1, b1, cur1);
  snn_loop<<<NBLK, 512, SMEM_BYTES, stream>>>(cur1, w2, b2, spk2_rec, mem2_rec);
}

// Round 12
// 200.376 us; speedup vs baseline: 1.0013x; 1.0013x over previous
//
#include <hip/hip_runtime.h>
#include <hip/hip_bf16.h>

// SNN: B=2048, NI=1024, NH=2048, NO=10, T=128, BETA=0.95, THR=1.0
// K1: cur1 = x @ w1^T + b1 via bf16x3 MFMA.
// K2: chunked LIF + time-as-M MFMA; GB=4, batch split across 2 waves.
// r12: __launch_bounds__(512,2) on BOTH kernels — (512,4) was interpreted as
// 4 blocks/CU -> 64-VGPR cap -> scratch spill (r11: VGPR 64, 2x hbm_bytes;
// r8 gemm: VGPR 28, FETCH 37MB). 128-VGPR cap fits both kernels' live state.

#define B_   2048
#define NI_  1024
#define NH_  2048
#define NO_  10
#define T_   128
#define GB_  4
#define NBLK (B_ / GB_)   // 512 blocks
#define TC_  32
#define NCH  (T_ / TC_)

typedef __attribute__((ext_vector_type(8))) short short8;
typedef __attribute__((ext_vector_type(4))) float f32x4;
typedef __attribute__((ext_vector_type(4))) unsigned int u32x4;

// bf16 round-to-nearest-even of an f32, low 16 bits.
__device__ __forceinline__ unsigned int bf16_rne(float f) {
  unsigned int u = __float_as_uint(f);
  return (u + 0x7FFFu + ((u >> 16) & 1u)) >> 16;
}

// ---------------- Kernel 1: cur1 = x @ w1^T + b1 (bf16x3 MFMA) --------------
#define G_ASTRIDE 144
#define G_AOFF    0
#define G_BOFF    (128 * G_ASTRIDE)
#define G_SMEM    (2 * 128 * G_ASTRIDE)

__global__ __launch_bounds__(512, 2) void gemm_cur1(
    const float* __restrict__ x, const float* __restrict__ w1,
    const float* __restrict__ b1, float* __restrict__ cur1) {
  __shared__ __align__(16) char smem[G_SMEM];
  const int tid = threadIdx.x;
  const int lane = tid & 63;
  const int wv = tid >> 6;
  const int wm = wv >> 2;
  const int wn = wv & 3;
  const int n15 = lane & 15;
  const int g = lane >> 4;
  const int brow = blockIdx.y * 128;
  const int bcol = blockIdx.x * 128;

  const int r_st = tid >> 3;
  const int kq = tid & 7;

  f32x4 acc[4][2];
#pragma unroll
  for (int tm = 0; tm < 4; ++tm)
#pragma unroll
    for (int tn = 0; tn < 2; ++tn) acc[tm][tn] = f32x4{0, 0, 0, 0};

  for (int kt = 0; kt < NI_; kt += 32) {
#pragma unroll
    for (int p = 0; p < 2; ++p) {
      const int r = r_st + p * 64;
      const float4 va = *reinterpret_cast<const float4*>(
          &x[(size_t)(brow + r) * NI_ + kt + kq * 4]);
      const float4 vb = *reinterpret_cast<const float4*>(
          &w1[(size_t)(bcol + r) * NI_ + kt + kq * 4]);
      const float fa[4] = {va.x, va.y, va.z, va.w};
      const float fb[4] = {vb.x, vb.y, vb.z, vb.w};
      unsigned ha[4], la[4], hb[4], lb[4];
#pragma unroll
      for (int c = 0; c < 4; ++c) {
        ha[c] = bf16_rne(fa[c]);
        la[c] = bf16_rne(fa[c] - __uint_as_float(ha[c] << 16));
        hb[c] = bf16_rne(fb[c]);
        lb[c] = bf16_rne(fb[c] - __uint_as_float(hb[c] << 16));
      }
      char* arow = smem + G_AOFF + r * G_ASTRIDE;
      char* brw  = smem + G_BOFF + r * G_ASTRIDE;
      *reinterpret_cast<uint2*>(arow + kq * 8) =
          uint2{ha[0] | (ha[1] << 16), ha[2] | (ha[3] << 16)};
      *reinterpret_cast<uint2*>(arow + 64 + kq * 8) =
          uint2{la[0] | (la[1] << 16), la[2] | (la[3] << 16)};
      *reinterpret_cast<uint2*>(brw + kq * 8) =
          uint2{hb[0] | (hb[1] << 16), hb[2] | (hb[3] << 16)};
      *reinterpret_cast<uint2*>(brw + 64 + kq * 8) =
          uint2{lb[0] | (lb[1] << 16), lb[2] | (lb[3] << 16)};
    }
    __syncthreads();

    short8 ah[4], al[4], bh2[2], bl2[2];
#pragma unroll
    for (int tm = 0; tm < 4; ++tm) {
      const char* p = smem + G_AOFF + (wm * 64 + tm * 16 + n15) * G_ASTRIDE;
      ah[tm] = *reinterpret_cast<const short8*>(p + g * 16);
      al[tm] = *reinterpret_cast<const short8*>(p + 64 + g * 16);
    }
#pragma unroll
    for (int tn = 0; tn < 2; ++tn) {
      const char* p = smem + G_BOFF + (wn * 32 + tn * 16 + n15) * G_ASTRIDE;
      bh2[tn] = *reinterpret_cast<const short8*>(p + g * 16);
      bl2[tn] = *reinterpret_cast<const short8*>(p + 64 + g * 16);
    }
#pragma unroll
    for (int tm = 0; tm < 4; ++tm)
#pragma unroll
      for (int tn = 0; tn < 2; ++tn) {
        acc[tm][tn] = __builtin_amdgcn_mfma_f32_16x16x32_bf16(
            ah[tm], bh2[tn], acc[tm][tn], 0, 0, 0);
        acc[tm][tn] = __builtin_amdgcn_mfma_f32_16x16x32_bf16(
            ah[tm], bl2[tn], acc[tm][tn], 0, 0, 0);
        acc[tm][tn] = __builtin_amdgcn_mfma_f32_16x16x32_bf16(
            al[tm], bh2[tn], acc[tm][tn], 0, 0, 0);
      }
    __syncthreads();
  }

#pragma unroll
  for (int tn = 0; tn < 2; ++tn) {
    const int col = bcol + wn * 32 + tn * 16 + n15;
    const float bias = b1[col];
#pragma unroll
    for (int tm = 0; tm < 4; ++tm) {
      const int rowb = brow + wm * 64 + tm * 16 + g * 4;
#pragma unroll
      for (int r = 0; r < 4; ++r)
        cur1[(size_t)(rowb + r) * NH_ + col] = acc[tm][tn][r] + bias;
    }
  }
}

// ---------------- Kernel 2: chunked LIF + time-as-M MFMA --------------------
// 8 waves: hf = w>>2 (neuron half), bq = w&3 (batch). Lane owns 16 neurons
// h = hf*1024 + lane*16 + i. Bits word k = h/32 = hf*32 + (lane>>1),
// halfword (lane&1).
// LDS map (bytes):
//   bits u32[4 b][32 tl][65]            at 0      (33280)
//   lut  uint2[16]                      at 33280  (128)
//   comb f32[8 w][4 b][2][4][10][4]     at 33408  (40960)
//   stag f32[4 b][32 tl][10]            at 74368  (5120)
#define BITS_OFF 0
#define LUT_OFF  33280
#define COMB_OFF 33408
#define STAG_OFF 74368
#define SMEM_BYTES 79488

__global__ __launch_bounds__(512, 2) void snn_loop(
    const float* __restrict__ cur1, const float* __restrict__ w2,
    const float* __restrict__ b2, float* __restrict__ spk2_rec,
    float* __restrict__ mem2_rec) {
  extern __shared__ char smem[];
  uint2* lutw = reinterpret_cast<uint2*>(smem + LUT_OFF);
  const uint2* lut = lutw;
  float* comb = reinterpret_cast<float*>(smem + COMB_OFF);
  float* stag = reinterpret_cast<float*>(smem + STAG_OFF);
  const int tid = threadIdx.x;
  const int lane = tid & 63;
  const int w = tid >> 6;
  const int hf = w >> 2;               // neuron half
  const int bq = w & 3;                // local batch
  const int bbase = blockIdx.x * GB_;
  const int bb = bbase + bq;

  if (tid < 16) {
    lutw[tid] = uint2{(tid & 1 ? 0x3F80u : 0u) | (tid & 2 ? 0x3F800000u : 0u),
                      (tid & 4 ? 0x3F80u : 0u) | (tid & 8 ? 0x3F800000u : 0u)};
  }

  // ---- layer-1 state: 16 contiguous h per lane ----
  float mem1[16], c1v[16], spk[16];
  {
    const float* base = cur1 + (size_t)bb * NH_ + hf * 1024 + lane * 16;
#pragma unroll
    for (int q = 0; q < 4; ++q) {
      const float4 v = *reinterpret_cast<const float4*>(base + q * 4);
      c1v[q * 4 + 0] = v.x; c1v[q * 4 + 1] = v.y;
      c1v[q * 4 + 2] = v.z; c1v[q * 4 + 3] = v.w;
    }
#pragma unroll
    for (int i = 0; i < 16; ++i) { mem1[i] = 0.0f; spk[i] = 0.0f; }
  }

  // ---- w2 B-fragments in registers (hi/lo split) — verified ----
  u32x4 bhi[8], blo[8];
  {
    const int o = lane & 15;
    const int koff = (lane >> 4) * 8;
#pragma unroll
    for (int kbl = 0; kbl < 8; ++kbl) {
      const int kb = w * 8 + kbl;
      unsigned int hw[4], lw[4];
#pragma unroll
      for (int p = 0; p < 4; ++p) {
        unsigned int h0 = 0, h1 = 0, l0 = 0, l1 = 0;
        if (o < NO_) {
          const int k = kb * 32 + koff + p * 2;
          const float f0 = w2[(size_t)o * NH_ + k];
          const float f1 = w2[(size_t)o * NH_ + k + 1];
          h0 = bf16_rne(f0);
          h1 = bf16_rne(f1);
          l0 = bf16_rne(f0 - __uint_as_float(h0 << 16));
          l1 = bf16_rne(f1 - __uint_as_float(h1 << 16));
        }
        hw[p] = h0 | (h1 << 16);
        lw[p] = l0 | (l1 << 16);
      }
      bhi[kbl] = u32x4{hw[0], hw[1], hw[2], hw[3]};
      blo[kbl] = u32x4{lw[0], lw[1], lw[2], lw[3]};
    }
  }

  // ---- layer-2 state: wave bq (hf==0), lanes < NO_ ----
  float mem2 = 0.0f, spk2 = 0.0f, b2v = 0.0f;
  float *srec = nullptr, *mrec = nullptr;
  if (hf == 0 && lane < NO_) {
    b2v = b2[lane];
    srec = spk2_rec + (size_t)bb * NO_ + lane;
    mrec = mem2_rec + (size_t)bb * NO_ + lane;
  }

  const int n15 = lane & 15;
  const int g = lane >> 4;

  // ---- phase-3' per-lane offsets (hf==0 waves only use these) ----
  int rd_off[5], wr_off[5];
#pragma unroll
  for (int j = 0; j < 5; ++j) {
    const int q = lane * 5 + j;          // 0..319 within batch bq
    const int tb = q / 160;
    const int r160 = q - tb * 160;
    const int g2 = r160 / 40;
    const int r40 = r160 - g2 * 40;
    const int n = r40 >> 2;
    const int r = r40 & 3;
    rd_off[j] = bq * 320 + q;            // + ww*1280 in the loop
    wr_off[j] = (bq * TC_ + tb * 16 + g2 * 4 + r) * 10 + n;
  }

  // bits halfword pointer: word (bq*32+tl)*65 + hf*32 + (lane>>1), half lane&1
  unsigned short* bitsw = reinterpret_cast<unsigned short*>(smem) +
      ((bq * TC_) * 65 + hf * 32 + (lane >> 1)) * 2 + (lane & 1);
  const unsigned char* bytes = reinterpret_cast<const unsigned char*>(smem);

  for (int ch = 0; ch < NCH; ++ch) {
    // ---- phase 1: LIF for TC_ steps; descending-i addc bit collect ----
    for (int tl = 0; tl < TC_; ++tl) {
      unsigned W = 0;
#pragma unroll
      for (int i = 15; i >= 0; --i) {
        float m = fmaf(0.95f, mem1[i], c1v[i]);
        m = m - spk[i];
        mem1[i] = m;
        const bool c = m > 1.0f;
        W = W + W + (c ? 1u : 0u);
        spk[i] = c ? 1.0f : 0.0f;
      }
      bitsw[tl * 130] = (unsigned short)W;
    }
    __syncthreads();  // B1: bits ready (also fences comb vs prev P3')

    // ---- phase 2: MFMA partials over this wave's K-chunk, 4 batches ----
    for (int b = 0; b < GB_; ++b) {
#pragma unroll
      for (int tb = 0; tb < 2; ++tb) {
        f32x4 acc = {0.0f, 0.0f, 0.0f, 0.0f};
#pragma unroll
        for (int kbl = 0; kbl < 8; ++kbl) {
          const int kb = w * 8 + kbl;
          const unsigned byt =
              bytes[(b * 2080 + tb * 1040 + n15 * 65 + kb) * 4 + g];
          const uint2 lo2 = lut[byt & 15u];
          const uint2 hi2 = lut[byt >> 4];
          const u32x4 A = {lo2.x, lo2.y, hi2.x, hi2.y};
          const short8 af = __builtin_bit_cast(short8, A);
          acc = __builtin_amdgcn_mfma_f32_16x16x32_bf16(
              af, __builtin_bit_cast(short8, bhi[kbl]), acc, 0, 0, 0);
          acc = __builtin_amdgcn_mfma_f32_16x16x32_bf16(
              af, __builtin_bit_cast(short8, blo[kbl]), acc, 0, 0, 0);
        }
        if (n15 < NO_)
          *reinterpret_cast<f32x4*>(
              &comb[w * 1280 + b * 320 + tb * 160 + g * 40 + n15 * 4]) = acc;
      }
    }
    __syncthreads();  // B2: comb ready; bits dead

    if (hf == 0) {
      // ---- phase 3': sum 8 wave-partials for OWN batch -> stag ----
#pragma unroll
      for (int j = 0; j < 5; ++j) {
        float s = 0.0f;
#pragma unroll
        for (int ww = 0; ww < 8; ++ww) s += comb[ww * 1280 + rd_off[j]];
        stag[wr_off[j]] = s;
      }
      // stag slice [bq] written and read only by this wave (lgkmcnt)

      // ---- phase 4: mem2 scan ----
      if (lane < NO_) {
        for (int tl = 0; tl < TC_; ++tl) {
          const float cur2 = stag[(bq * TC_ + tl) * 10 + lane] + b2v;
          float m = fmaf(0.95f, mem2, cur2);
          m = m - spk2;
          mem2 = m;
          spk2 = (m > 1.0f) ? 1.0f : 0.0f;
          const int t = ch * TC_ + tl;
          srec[(size_t)t * (B_ * NO_)] = spk2;
          mrec[(size_t)t * (B_ * NO_)] = m;
        }
      }
    }
    // no barrier: next P1 writes bits (dead since B2); comb overwrite is
    // fenced by the next B1; stag/comb reads are done before this wave's B1.
  }
}

// ---------------------------------------------------------------------------
extern "C" void kernel_launch(void* const* d_in, const int* in_sizes, int n_in,
                              void* d_out, int out_size, void* d_ws, size_t ws_size,
                              hipStream_t stream) {
  const float* x  = (const float*)d_in[0];
  const float* w1 = (const float*)d_in[1];
  const float* b1 = (const float*)d_in[2];
  const float* w2 = (const float*)d_in[3];
  const float* b2 = (const float*)d_in[4];
  float* out = (float*)d_out;
  float* cur1 = (float*)d_ws;

  float* spk2_rec = out;
  float* mem2_rec = out + (size_t)T_ * B_ * NO_;

  (void)hipFuncSetAttribute(reinterpret_cast<const void*>(snn_loop),
                            hipFuncAttributeMaxDynamicSharedMemorySize,
                            SMEM_BYTES);

  dim3 g1(NH_ / 128, B_ / 128);
  gemm_cur1<<<g1, 512, 0, stream>>>(x, w1, b1, cur1);
  snn_loop<<<NBLK, 512, SMEM_BYTES, stream>>>(cur1, w2, b2, spk2_rec, mem2_rec);
}